// Round 14
// baseline (205.745 us; speedup 1.0000x reference)
//
#include <hip/hip_runtime.h>

#define F_IN 64
#define NH 4
#define HC 128
#define NEG_SLOPE 0.2f
#define LN_EPS 1e-5f
#define NC_CHUNK 256          // number of edge chunks
#define BUCKET 128            // dst nodes per bucket
#define KW_BLOCKS 64          // blocks doing the W transpose in k_prep

typedef __bf16 bf16_8 __attribute__((ext_vector_type(8)));
typedef float  f32_4  __attribute__((ext_vector_type(4)));

// ---------------------------------------------------------------------------
// Inline per-wave int64-vs-int32 detection (all-zero odd dwords <=> int64).
// ---------------------------------------------------------------------------
__device__ inline int detect_is64(const int* __restrict__ ei, int E) {
    int lane = threadIdx.x & 63;
    long long stride = (2LL * E) / 65;
    int w = ei[(((long long)(lane + 1)) * stride) | 1];
    return __ballot(w != 0) == 0ULL;
}

__device__ inline unsigned bfpack(float a, float b) {
    unsigned ua = __float_as_uint(a), ub = __float_as_uint(b);
    ua = (ua + 0x7fffu + ((ua >> 16) & 1u)) >> 16;           // RNE to bf16
    ub = (ub + 0x7fffu + ((ub >> 16) & 1u)) >> 16;
    return ua | (ub << 16);
}

// ---------------------------------------------------------------------------
// K_prep: blocks [0,64) transpose Wcat -> bf16 wt; blocks [64,64+NC_CHUNK)
// per-chunk dst-bucket histogram -> counts[c*NB+b].
// ---------------------------------------------------------------------------
__global__ __launch_bounds__(256) void k_prep(
    const float* __restrict__ W, const float* __restrict__ res_w,
    const int* __restrict__ ei, int E,
    __bf16* __restrict__ wt, int* __restrict__ counts, int NB, int chunk)
{
    if ((int)blockIdx.x < KW_BLOCKS) {
        int idx = blockIdx.x * 256 + threadIdx.x;    // 0..16383
        int ch = idx >> 6, k = idx & 63;
        const float* src = (ch < HC) ? W : res_w;
        wt[ch * 64 + k] = (__bf16)src[k * HC + (ch & (HC - 1))];
        return;
    }
    __shared__ int cnt[512];
    int c = blockIdx.x - KW_BLOCKS;
    for (int i = threadIdx.x; i < NB; i += 256) cnt[i] = 0;
    __syncthreads();
    int is64 = detect_is64(ei, E);
    int base = c * chunk, end = min(E, base + chunk);
    for (int idx = base + threadIdx.x; idx < end; idx += 256) {
        int d = is64 ? ei[2 * (E + idx)] : ei[E + idx];
        atomicAdd(&cnt[d >> 7], 1);
    }
    __syncthreads();
    for (int b = threadIdx.x; b < NB; b += 256)
        counts[c * NB + b] = cnt[b];
}

// ---------------------------------------------------------------------------
// K_main: blocks [0,nka): kA MFMA dual-GEMM (1 node-set/wave, 64 nodes/block,
//         proven R11/R12 body); blocks [nka,nka+NC_CHUNK): kc_scatter.
// ---------------------------------------------------------------------------
__global__ __launch_bounds__(256) void k_main(
    const float* __restrict__ x, const __bf16* __restrict__ wt,
    const float* __restrict__ att_src, const float* __restrict__ att_dst,
    unsigned* __restrict__ h_bf, unsigned* __restrict__ r_bf,
    float* __restrict__ a_s, float* __restrict__ a_d, int n, int nka,
    const int* __restrict__ ei, int E, const int* __restrict__ counts,
    int* __restrict__ epacked, int* __restrict__ sbase_g, int NB, int chunk)
{
    __shared__ int cur[512];
    __shared__ int ss[256];

    if ((int)blockIdx.x < nka) {
        // ---------------- kA path (proven layout) ----------------
        int tid = threadIdx.x;
        int wv_ = tid >> 6, lane = tid & 63;
        int col = lane & 15, quad = lane >> 4;
        int node = blockIdx.x * 64 + wv_ * 16 + col;
        int nrow = (node < n) ? node : (n - 1);

        bf16_8 bx0, bx1;
        {
            const float* xp = &x[nrow * F_IN + quad * 8];
            float4 p0 = *(const float4*)(xp);
            float4 p1 = *(const float4*)(xp + 4);
            float4 p2 = *(const float4*)(xp + 32);
            float4 p3 = *(const float4*)(xp + 36);
            bx0[0] = (__bf16)p0.x; bx0[1] = (__bf16)p0.y; bx0[2] = (__bf16)p0.z; bx0[3] = (__bf16)p0.w;
            bx0[4] = (__bf16)p1.x; bx0[5] = (__bf16)p1.y; bx0[6] = (__bf16)p1.z; bx0[7] = (__bf16)p1.w;
            bx1[0] = (__bf16)p2.x; bx1[1] = (__bf16)p2.y; bx1[2] = (__bf16)p2.z; bx1[3] = (__bf16)p2.w;
            bx1[4] = (__bf16)p3.x; bx1[5] = (__bf16)p3.y; bx1[6] = (__bf16)p3.z; bx1[7] = (__bf16)p3.w;
        }

        float vs[4] = {0.f, 0.f, 0.f, 0.f};
        float vd[4] = {0.f, 0.f, 0.f, 0.f};

#pragma unroll
        for (int mt = 0; mt < 16; ++mt) {
            const __bf16* ap = &wt[(mt * 16 + col) * 64 + quad * 8];
            bf16_8 a0 = *(const bf16_8*)ap;
            bf16_8 a1 = *(const bf16_8*)(ap + 32);
            f32_4 acc = {0.f, 0.f, 0.f, 0.f};
            acc = __builtin_amdgcn_mfma_f32_16x16x32_bf16(a0, bx0, acc, 0, 0, 0);
            acc = __builtin_amdgcn_mfma_f32_16x16x32_bf16(a1, bx1, acc, 0, 0, 0);
            int ch0 = mt * 16 + quad * 4;
            if (mt < 8) {
                float4 as4 = *(const float4*)&att_src[ch0];
                float4 ad4 = *(const float4*)&att_dst[ch0];
                int head = mt >> 1;
                vs[head] += acc[0] * as4.x + acc[1] * as4.y + acc[2] * as4.z + acc[3] * as4.w;
                vd[head] += acc[0] * ad4.x + acc[1] * ad4.y + acc[2] * ad4.z + acc[3] * ad4.w;
                if (node < n) {
                    uint2 pk = make_uint2(bfpack(acc[0], acc[1]), bfpack(acc[2], acc[3]));
                    *(uint2*)&h_bf[node * 64 + (ch0 >> 1)] = pk;
                }
            } else {
                if (node < n) {
                    uint2 pk = make_uint2(bfpack(acc[0], acc[1]), bfpack(acc[2], acc[3]));
                    *(uint2*)&r_bf[node * 64 + ((ch0 - 128) >> 1)] = pk;
                }
            }
        }

#pragma unroll
        for (int hh = 0; hh < NH; ++hh) {
            vs[hh] += __shfl_down(vs[hh], 32, 64);
            vs[hh] += __shfl_down(vs[hh], 16, 64);
            vd[hh] += __shfl_down(vd[hh], 32, 64);
            vd[hh] += __shfl_down(vd[hh], 16, 64);
        }
        if (quad == 0 && node < n) {
            *(float4*)&a_s[node * NH] = make_float4(vs[0], vs[1], vs[2], vs[3]);
            *(float4*)&a_d[node * NH] = make_float4(vd[0], vd[1], vd[2], vd[3]);
        }
        return;
    }

    // ---------------- scatter path ----------------
    int c = blockIdx.x - nka;
    int t = threadIdx.x;
    int b0 = 2 * t, b1 = 2 * t + 1;

    int f0 = 0, f1 = 0, p0 = 0, p1 = 0;
    for (int cc = 0; cc < NC_CHUNK; ++cc) {
        int v0 = (b0 < NB) ? counts[cc * NB + b0] : 0;
        int v1 = (b1 < NB) ? counts[cc * NB + b1] : 0;
        f0 += v0; f1 += v1;
        if (cc < c) { p0 += v0; p1 += v1; }
    }
    ss[t] = f0 + f1;
    __syncthreads();
#pragma unroll
    for (int off = 1; off < 256; off <<= 1) {
        int u = (t >= off) ? ss[t - off] : 0;
        __syncthreads();
        ss[t] += u;
        __syncthreads();
    }
    int ebase = ss[t] - (f0 + f1);
    int base0 = ebase, base1 = ebase + f0;
    if (b0 < NB) cur[b0] = base0 + p0;
    if (b1 < NB) cur[b1] = base1 + p1;
    if (c == 0) {
        if (b0 <= NB) sbase_g[b0] = base0;
        if (b1 <= NB) sbase_g[b1] = base1;
    }
    __syncthreads();

    int is64 = detect_is64(ei, E);
    int base = c * chunk, end = min(E, base + chunk);
    for (int idx = base + t; idx < end; idx += 256) {
        int s = is64 ? ei[2 * idx] : ei[idx];
        int d = is64 ? ei[2 * (E + idx)] : ei[E + idx];
        int p = atomicAdd(&cur[d >> 7], 1);
        epacked[p] = ((d & (BUCKET - 1)) << 16) | s;
    }
}

// ---------------------------------------------------------------------------
// KD_sort: one block per bucket -> per-dst CSR order; emits node offsets.
// ---------------------------------------------------------------------------
__global__ __launch_bounds__(256) void kd_sort(
    const int* __restrict__ sbase_g, const int* __restrict__ epacked,
    int* __restrict__ sorted_src, int* __restrict__ offsets,
    int NB, int n, int E)
{
    __shared__ int hist[BUCKET];
    __shared__ int sc[BUCKET];
    __shared__ int cur[BUCKET];
    int b = blockIdx.x;
    int s0 = sbase_g[b];
    int s1 = sbase_g[b + 1];
    int t = threadIdx.x;
    if (t < BUCKET) hist[t] = 0;
    __syncthreads();
    for (int e = s0 + t; e < s1; e += 256)
        atomicAdd(&hist[((unsigned)epacked[e]) >> 16], 1);
    __syncthreads();
    if (t < BUCKET) sc[t] = hist[t];
    __syncthreads();
#pragma unroll
    for (int o = 1; o < BUCKET; o <<= 1) {
        int u = (t >= o && t < BUCKET) ? sc[t - o] : 0;
        __syncthreads();
        if (t < BUCKET) sc[t] += u;
        __syncthreads();
    }
    if (t < BUCKET) {
        int excl = sc[t] - hist[t];
        cur[t] = s0 + excl;
        int d = b * BUCKET + t;
        if (d < n) offsets[d] = s0 + excl;
    }
    if (b == NB - 1 && t == 0) offsets[n] = E;
    __syncthreads();
    for (int e = s0 + t; e < s1; e += 256) {
        int p = epacked[e];
        int pos = atomicAdd(&cur[((unsigned)p) >> 16], 1);
        sorted_src[pos] = p & 0xFFFF;
    }
}

// ---------------------------------------------------------------------------
// K_agg: wave-per-dst, 4 EDGES per iteration-slot (eq = lane>>4 selects edge,
// g = lane&15 -> 8 channels via uint4). Merge via shfl_xor(16)+shfl_xor(32).
// Register accumulation, no atomics, fused epilogue.
// ---------------------------------------------------------------------------
__global__ __launch_bounds__(256) void k_agg(
    const int* __restrict__ offsets, const int* __restrict__ src_sorted,
    const float* __restrict__ a_s, const float* __restrict__ a_d,
    const unsigned int* __restrict__ h_bf, const unsigned int* __restrict__ r_bf,
    const float* __restrict__ bias, const float* __restrict__ res_b,
    const float* __restrict__ ln_g, const float* __restrict__ ln_b,
    float* __restrict__ out, int n)
{
    int wv = threadIdx.x >> 6, lane = threadIdx.x & 63;
    int d = blockIdx.x * 4 + wv;
    if (d >= n) return;
    int eq = lane >> 4, g = lane & 15;       // edge-quarter, channel group (8 ch)
    int head = g >> 2;                       // channels g*8..g*8+7 in one head
    float ad = a_d[d * NH + head];

    float a0 = 0.f, a1 = 0.f, a2 = 0.f, a3 = 0.f;
    float a4 = 0.f, a5 = 0.f, a6 = 0.f, a7 = 0.f, denom = 0.f;

    // self-loop on eq=0 quarter only
    {
        float e = a_s[d * NH + head] + ad;
        e = (e >= 0.f) ? e : NEG_SLOPE * e;
        float w = (eq == 0) ? __expf(e) : 0.f;
        uint4 hv = *(const uint4*)&h_bf[d * 64 + g * 4];
        a0 += w * __uint_as_float(hv.x << 16);
        a1 += w * __uint_as_float(hv.x & 0xffff0000u);
        a2 += w * __uint_as_float(hv.y << 16);
        a3 += w * __uint_as_float(hv.y & 0xffff0000u);
        a4 += w * __uint_as_float(hv.z << 16);
        a5 += w * __uint_as_float(hv.z & 0xffff0000u);
        a6 += w * __uint_as_float(hv.w << 16);
        a7 += w * __uint_as_float(hv.w & 0xffff0000u);
        denom += w;
    }

    int lo = offsets[d], hi = offsets[d + 1];
    int k = lo;
    // main loop: 2 slots x 4 quarters = 8 edges, all in-range
    for (; k + 7 < hi; k += 8) {
        int s[2]; float ee[2]; uint4 v[2];
#pragma unroll
        for (int i = 0; i < 2; ++i) s[i] = src_sorted[k + 4 * i + eq];
#pragma unroll
        for (int i = 0; i < 2; ++i) ee[i] = a_s[s[i] * NH + head];
#pragma unroll
        for (int i = 0; i < 2; ++i) v[i] = *(const uint4*)&h_bf[s[i] * 64 + g * 4];
#pragma unroll
        for (int i = 0; i < 2; ++i) {
            float e0 = ee[i] + ad;
            e0 = (e0 >= 0.f) ? e0 : NEG_SLOPE * e0;
            float w0 = __expf(e0);
            denom += w0;
            a0 += w0 * __uint_as_float(v[i].x << 16);
            a1 += w0 * __uint_as_float(v[i].x & 0xffff0000u);
            a2 += w0 * __uint_as_float(v[i].y << 16);
            a3 += w0 * __uint_as_float(v[i].y & 0xffff0000u);
            a4 += w0 * __uint_as_float(v[i].z << 16);
            a5 += w0 * __uint_as_float(v[i].z & 0xffff0000u);
            a6 += w0 * __uint_as_float(v[i].w << 16);
            a7 += w0 * __uint_as_float(v[i].w & 0xffff0000u);
        }
    }
    // tail: quads with per-lane guard
    for (; k < hi; k += 4) {
        int idx = k + eq;
        int valid = idx < hi;
        int s0 = valid ? src_sorted[idx] : 0;
        float e0 = a_s[s0 * NH + head] + ad;
        uint4 v0 = *(const uint4*)&h_bf[s0 * 64 + g * 4];
        e0 = (e0 >= 0.f) ? e0 : NEG_SLOPE * e0;
        float w0 = valid ? __expf(e0) : 0.f;
        denom += w0;
        a0 += w0 * __uint_as_float(v0.x << 16);
        a1 += w0 * __uint_as_float(v0.x & 0xffff0000u);
        a2 += w0 * __uint_as_float(v0.y << 16);
        a3 += w0 * __uint_as_float(v0.y & 0xffff0000u);
        a4 += w0 * __uint_as_float(v0.z << 16);
        a5 += w0 * __uint_as_float(v0.z & 0xffff0000u);
        a6 += w0 * __uint_as_float(v0.w << 16);
        a7 += w0 * __uint_as_float(v0.w & 0xffff0000u);
    }

    // merge the 4 edge-quarters (lane bits 4 and 5)
    a0 += __shfl_xor(a0, 16, 64); a0 += __shfl_xor(a0, 32, 64);
    a1 += __shfl_xor(a1, 16, 64); a1 += __shfl_xor(a1, 32, 64);
    a2 += __shfl_xor(a2, 16, 64); a2 += __shfl_xor(a2, 32, 64);
    a3 += __shfl_xor(a3, 16, 64); a3 += __shfl_xor(a3, 32, 64);
    a4 += __shfl_xor(a4, 16, 64); a4 += __shfl_xor(a4, 32, 64);
    a5 += __shfl_xor(a5, 16, 64); a5 += __shfl_xor(a5, 32, 64);
    a6 += __shfl_xor(a6, 16, 64); a6 += __shfl_xor(a6, 32, 64);
    a7 += __shfl_xor(a7, 16, 64); a7 += __shfl_xor(a7, 32, 64);
    denom += __shfl_xor(denom, 16, 64); denom += __shfl_xor(denom, 32, 64);

    int c0 = g * 8;
    float4 biA = *(const float4*)&bias[c0],  biB = *(const float4*)&bias[c0 + 4];
    float4 rbA = *(const float4*)&res_b[c0], rbB = *(const float4*)&res_b[c0 + 4];
    float4 ggA = *(const float4*)&ln_g[c0],  ggB = *(const float4*)&ln_g[c0 + 4];
    float4 lbA = *(const float4*)&ln_b[c0],  lbB = *(const float4*)&ln_b[c0 + 4];
    uint4 rv = *(const uint4*)&r_bf[d * 64 + g * 4];

    float inv = 1.f / denom;
    float o0 = a0 * inv + biA.x, o1 = a1 * inv + biA.y;
    float o2 = a2 * inv + biA.z, o3 = a3 * inv + biA.w;
    float o4 = a4 * inv + biB.x, o5 = a5 * inv + biB.y;
    float o6 = a6 * inv + biB.z, o7 = a7 * inv + biB.w;
    o0 = (o0 > 0.f) ? o0 : expm1f(o0);
    o1 = (o1 > 0.f) ? o1 : expm1f(o1);
    o2 = (o2 > 0.f) ? o2 : expm1f(o2);
    o3 = (o3 > 0.f) ? o3 : expm1f(o3);
    o4 = (o4 > 0.f) ? o4 : expm1f(o4);
    o5 = (o5 > 0.f) ? o5 : expm1f(o5);
    o6 = (o6 > 0.f) ? o6 : expm1f(o6);
    o7 = (o7 > 0.f) ? o7 : expm1f(o7);
    o0 += __uint_as_float(rv.x << 16) + rbA.x;
    o1 += __uint_as_float(rv.x & 0xffff0000u) + rbA.y;
    o2 += __uint_as_float(rv.y << 16) + rbA.z;
    o3 += __uint_as_float(rv.y & 0xffff0000u) + rbA.w;
    o4 += __uint_as_float(rv.z << 16) + rbB.x;
    o5 += __uint_as_float(rv.z & 0xffff0000u) + rbB.y;
    o6 += __uint_as_float(rv.w << 16) + rbB.z;
    o7 += __uint_as_float(rv.w & 0xffff0000u) + rbB.w;

    // LN: 4x duplication -> full-wave sum = 4x channel total
    float ps = ((o0 + o1) + (o2 + o3)) + ((o4 + o5) + (o6 + o7));
#pragma unroll
    for (int off = 32; off > 0; off >>= 1) ps += __shfl_down(ps, off, 64);
    float mean = __shfl(ps, 0, 64) * (1.f / (4 * HC));
    float d0 = o0 - mean, d1 = o1 - mean, d2 = o2 - mean, d3 = o3 - mean;
    float d4 = o4 - mean, d5 = o5 - mean, d6 = o6 - mean, d7 = o7 - mean;
    float pv = ((d0*d0 + d1*d1) + (d2*d2 + d3*d3)) + ((d4*d4 + d5*d5) + (d6*d6 + d7*d7));
#pragma unroll
    for (int off = 32; off > 0; off >>= 1) pv += __shfl_down(pv, off, 64);
    float var = __shfl(pv, 0, 64) * (1.f / (4 * HC));
    float rs = rsqrtf(var + LN_EPS);
    if (eq == 0) {
        *(float4*)&out[d * HC + c0] =
            make_float4(ggA.x * d0 * rs + lbA.x, ggA.y * d1 * rs + lbA.y,
                        ggA.z * d2 * rs + lbA.z, ggA.w * d3 * rs + lbA.w);
        *(float4*)&out[d * HC + c0 + 4] =
            make_float4(ggB.x * d4 * rs + lbB.x, ggB.y * d5 * rs + lbB.y,
                        ggB.z * d6 * rs + lbB.z, ggB.w * d7 * rs + lbB.w);
    }
}

// ---------------------------------------------------------------------------
extern "C" void kernel_launch(void* const* d_in, const int* in_sizes, int n_in,
                              void* d_out, int out_size, void* d_ws, size_t ws_size,
                              hipStream_t stream) {
    const float* x       = (const float*)d_in[0];
    const int*   ei      = (const int*)d_in[1];
    const float* W       = (const float*)d_in[2];
    const float* att_src = (const float*)d_in[3];
    const float* att_dst = (const float*)d_in[4];
    const float* bias    = (const float*)d_in[5];
    const float* res_w   = (const float*)d_in[6];
    const float* res_b   = (const float*)d_in[7];
    const float* ln_g    = (const float*)d_in[8];
    const float* ln_b    = (const float*)d_in[9];
    float* out = (float*)d_out;

    int n = in_sizes[0] / F_IN;              // 50000 (<= 65536 for packing)
    int E = in_sizes[1] / 2;                 // 800000
    int NB = (n + BUCKET - 1) / BUCKET;      // 391 buckets (<= 512)
    int chunk = (E + NC_CHUNK - 1) / NC_CHUNK;
    int nka = (n + 63) / 64;                 // 782 kA blocks (1 set/wave)

    unsigned* h_bf     = (unsigned*)d_ws;                  // n*64 dwords
    unsigned* r_bf     = h_bf + (size_t)n * 64;            // n*64 dwords
    float*    a_s      = (float*)(r_bf + (size_t)n * 64);  // n*NH
    float*    a_d      = a_s + (size_t)n * NH;             // n*NH
    int*      counts   = (int*)(a_d + (size_t)n * NH);     // NC_CHUNK*NB
    int*      sbase_g  = counts + NC_CHUNK * NB;           // NB+1
    int*      epacked  = sbase_g + (NB + 2);               // E
    int*      ssorted  = epacked + E;                      // E
    int*      offsets  = ssorted + E;                      // n+1
    __bf16*   wt       = (__bf16*)(offsets + (n + 2));     // 256*64 bf16 = 32 KB

    k_prep<<<KW_BLOCKS + NC_CHUNK, 256, 0, stream>>>(
        W, res_w, ei, E, wt, counts, NB, chunk);

    k_main<<<nka + NC_CHUNK, 256, 0, stream>>>(
        x, wt, att_src, att_dst, h_bf, r_bf, a_s, a_d, n, nka,
        ei, E, counts, epacked, sbase_g, NB, chunk);

    kd_sort<<<NB, 256, 0, stream>>>(sbase_g, epacked, ssorted, offsets, NB, n, E);

    k_agg<<<(n + 3) / 4, 256, 0, stream>>>(offsets, ssorted, a_s, a_d, h_bf, r_bf,
                                           bias, res_b, ln_g, ln_b, out, n);
}

// Round 15
// 189.010 us; speedup vs baseline: 1.0885x; 1.0885x over previous
//
#include <hip/hip_runtime.h>

#define F_IN 64
#define NH 4
#define HC 128
#define NEG_SLOPE 0.2f
#define LN_EPS 1e-5f
#define NC_CHUNK 128          // number of edge chunks (quadratic prefix cost!)
#define BUCKET 128            // dst nodes per bucket
#define KW_BLOCKS 64          // blocks doing the W transpose in k_prep

typedef __bf16 bf16_8 __attribute__((ext_vector_type(8)));
typedef float  f32_4  __attribute__((ext_vector_type(4)));

// ---------------------------------------------------------------------------
// Inline per-wave int64-vs-int32 detection (all-zero odd dwords <=> int64).
// ---------------------------------------------------------------------------
__device__ inline int detect_is64(const int* __restrict__ ei, int E) {
    int lane = threadIdx.x & 63;
    long long stride = (2LL * E) / 65;
    int w = ei[(((long long)(lane + 1)) * stride) | 1];
    return __ballot(w != 0) == 0ULL;
}

__device__ inline unsigned bfpack(float a, float b) {
    unsigned ua = __float_as_uint(a), ub = __float_as_uint(b);
    ua = (ua + 0x7fffu + ((ua >> 16) & 1u)) >> 16;           // RNE to bf16
    ub = (ub + 0x7fffu + ((ub >> 16) & 1u)) >> 16;
    return ua | (ub << 16);
}

// ---------------------------------------------------------------------------
// K_prep: blocks [0,64) transpose Wcat -> bf16 wt; blocks [64,64+NC_CHUNK)
// per-chunk dst-bucket histogram -> counts[c*NB+b].   (R12-proven)
// ---------------------------------------------------------------------------
__global__ __launch_bounds__(256) void k_prep(
    const float* __restrict__ W, const float* __restrict__ res_w,
    const int* __restrict__ ei, int E,
    __bf16* __restrict__ wt, int* __restrict__ counts, int NB, int chunk)
{
    if ((int)blockIdx.x < KW_BLOCKS) {
        int idx = blockIdx.x * 256 + threadIdx.x;    // 0..16383
        int ch = idx >> 6, k = idx & 63;
        const float* src = (ch < HC) ? W : res_w;
        wt[ch * 64 + k] = (__bf16)src[k * HC + (ch & (HC - 1))];
        return;
    }
    __shared__ int cnt[512];
    int c = blockIdx.x - KW_BLOCKS;
    for (int i = threadIdx.x; i < NB; i += 256) cnt[i] = 0;
    __syncthreads();
    int is64 = detect_is64(ei, E);
    int base = c * chunk, end = min(E, base + chunk);
    for (int idx = base + threadIdx.x; idx < end; idx += 256) {
        int d = is64 ? ei[2 * (E + idx)] : ei[E + idx];
        atomicAdd(&cnt[d >> 7], 1);
    }
    __syncthreads();
    for (int b = threadIdx.x; b < NB; b += 256)
        counts[c * NB + b] = cnt[b];
}

// ---------------------------------------------------------------------------
// K_main: blocks [0,nka): kA MFMA dual-GEMM (1 node-set/wave, 64 nodes/block);
//         blocks [nka,nka+NC_CHUNK): kc_scatter.   (R12-proven bodies)
// ---------------------------------------------------------------------------
__global__ __launch_bounds__(256) void k_main(
    const float* __restrict__ x, const __bf16* __restrict__ wt,
    const float* __restrict__ att_src, const float* __restrict__ att_dst,
    unsigned* __restrict__ h_bf, unsigned* __restrict__ r_bf,
    float* __restrict__ a_s, float* __restrict__ a_d, int n, int nka,
    const int* __restrict__ ei, int E, const int* __restrict__ counts,
    int* __restrict__ epacked, int* __restrict__ sbase_g, int NB, int chunk)
{
    __shared__ int cur[512];
    __shared__ int ss[256];

    if ((int)blockIdx.x < nka) {
        // ---------------- kA path (proven layout) ----------------
        int tid = threadIdx.x;
        int wv_ = tid >> 6, lane = tid & 63;
        int col = lane & 15, quad = lane >> 4;
        int node = blockIdx.x * 64 + wv_ * 16 + col;
        int nrow = (node < n) ? node : (n - 1);

        bf16_8 bx0, bx1;
        {
            const float* xp = &x[nrow * F_IN + quad * 8];
            float4 p0 = *(const float4*)(xp);
            float4 p1 = *(const float4*)(xp + 4);
            float4 p2 = *(const float4*)(xp + 32);
            float4 p3 = *(const float4*)(xp + 36);
            bx0[0] = (__bf16)p0.x; bx0[1] = (__bf16)p0.y; bx0[2] = (__bf16)p0.z; bx0[3] = (__bf16)p0.w;
            bx0[4] = (__bf16)p1.x; bx0[5] = (__bf16)p1.y; bx0[6] = (__bf16)p1.z; bx0[7] = (__bf16)p1.w;
            bx1[0] = (__bf16)p2.x; bx1[1] = (__bf16)p2.y; bx1[2] = (__bf16)p2.z; bx1[3] = (__bf16)p2.w;
            bx1[4] = (__bf16)p3.x; bx1[5] = (__bf16)p3.y; bx1[6] = (__bf16)p3.z; bx1[7] = (__bf16)p3.w;
        }

        float vs[4] = {0.f, 0.f, 0.f, 0.f};
        float vd[4] = {0.f, 0.f, 0.f, 0.f};

#pragma unroll
        for (int mt = 0; mt < 16; ++mt) {
            const __bf16* ap = &wt[(mt * 16 + col) * 64 + quad * 8];
            bf16_8 a0 = *(const bf16_8*)ap;
            bf16_8 a1 = *(const bf16_8*)(ap + 32);
            f32_4 acc = {0.f, 0.f, 0.f, 0.f};
            acc = __builtin_amdgcn_mfma_f32_16x16x32_bf16(a0, bx0, acc, 0, 0, 0);
            acc = __builtin_amdgcn_mfma_f32_16x16x32_bf16(a1, bx1, acc, 0, 0, 0);
            int ch0 = mt * 16 + quad * 4;
            if (mt < 8) {
                float4 as4 = *(const float4*)&att_src[ch0];
                float4 ad4 = *(const float4*)&att_dst[ch0];
                int head = mt >> 1;
                vs[head] += acc[0] * as4.x + acc[1] * as4.y + acc[2] * as4.z + acc[3] * as4.w;
                vd[head] += acc[0] * ad4.x + acc[1] * ad4.y + acc[2] * ad4.z + acc[3] * ad4.w;
                if (node < n) {
                    uint2 pk = make_uint2(bfpack(acc[0], acc[1]), bfpack(acc[2], acc[3]));
                    *(uint2*)&h_bf[node * 64 + (ch0 >> 1)] = pk;
                }
            } else {
                if (node < n) {
                    uint2 pk = make_uint2(bfpack(acc[0], acc[1]), bfpack(acc[2], acc[3]));
                    *(uint2*)&r_bf[node * 64 + ((ch0 - 128) >> 1)] = pk;
                }
            }
        }

#pragma unroll
        for (int hh = 0; hh < NH; ++hh) {
            vs[hh] += __shfl_down(vs[hh], 32, 64);
            vs[hh] += __shfl_down(vs[hh], 16, 64);
            vd[hh] += __shfl_down(vd[hh], 32, 64);
            vd[hh] += __shfl_down(vd[hh], 16, 64);
        }
        if (quad == 0 && node < n) {
            *(float4*)&a_s[node * NH] = make_float4(vs[0], vs[1], vs[2], vs[3]);
            *(float4*)&a_d[node * NH] = make_float4(vd[0], vd[1], vd[2], vd[3]);
        }
        return;
    }

    // ---------------- scatter path ----------------
    int c = blockIdx.x - nka;
    int t = threadIdx.x;
    int b0 = 2 * t, b1 = 2 * t + 1;

    int f0 = 0, f1 = 0, p0 = 0, p1 = 0;
    for (int cc = 0; cc < NC_CHUNK; ++cc) {
        int v0 = (b0 < NB) ? counts[cc * NB + b0] : 0;
        int v1 = (b1 < NB) ? counts[cc * NB + b1] : 0;
        f0 += v0; f1 += v1;
        if (cc < c) { p0 += v0; p1 += v1; }
    }
    ss[t] = f0 + f1;
    __syncthreads();
#pragma unroll
    for (int off = 1; off < 256; off <<= 1) {
        int u = (t >= off) ? ss[t - off] : 0;
        __syncthreads();
        ss[t] += u;
        __syncthreads();
    }
    int ebase = ss[t] - (f0 + f1);
    int base0 = ebase, base1 = ebase + f0;
    if (b0 < NB) cur[b0] = base0 + p0;
    if (b1 < NB) cur[b1] = base1 + p1;
    if (c == 0) {
        if (b0 <= NB) sbase_g[b0] = base0;
        if (b1 <= NB) sbase_g[b1] = base1;
    }
    __syncthreads();

    int is64 = detect_is64(ei, E);
    int base = c * chunk, end = min(E, base + chunk);
    for (int idx = base + t; idx < end; idx += 256) {
        int s = is64 ? ei[2 * idx] : ei[idx];
        int d = is64 ? ei[2 * (E + idx)] : ei[E + idx];
        int p = atomicAdd(&cur[d >> 7], 1);
        epacked[p] = ((d & (BUCKET - 1)) << 16) | s;
    }
}

// ---------------------------------------------------------------------------
// KD_sort: one block per bucket -> per-dst CSR order; emits node offsets.
// ---------------------------------------------------------------------------
__global__ __launch_bounds__(256) void kd_sort(
    const int* __restrict__ sbase_g, const int* __restrict__ epacked,
    int* __restrict__ sorted_src, int* __restrict__ offsets,
    int NB, int n, int E)
{
    __shared__ int hist[BUCKET];
    __shared__ int sc[BUCKET];
    __shared__ int cur[BUCKET];
    int b = blockIdx.x;
    int s0 = sbase_g[b];
    int s1 = sbase_g[b + 1];
    int t = threadIdx.x;
    if (t < BUCKET) hist[t] = 0;
    __syncthreads();
    for (int e = s0 + t; e < s1; e += 256)
        atomicAdd(&hist[((unsigned)epacked[e]) >> 16], 1);
    __syncthreads();
    if (t < BUCKET) sc[t] = hist[t];
    __syncthreads();
#pragma unroll
    for (int o = 1; o < BUCKET; o <<= 1) {
        int u = (t >= o && t < BUCKET) ? sc[t - o] : 0;
        __syncthreads();
        if (t < BUCKET) sc[t] += u;
        __syncthreads();
    }
    if (t < BUCKET) {
        int excl = sc[t] - hist[t];
        cur[t] = s0 + excl;
        int d = b * BUCKET + t;
        if (d < n) offsets[d] = s0 + excl;
    }
    if (b == NB - 1 && t == 0) offsets[n] = E;
    __syncthreads();
    for (int e = s0 + t; e < s1; e += 256) {
        int p = epacked[e];
        int pos = atomicAdd(&cur[((unsigned)p) >> 16], 1);
        sorted_src[pos] = p & 0xFFFF;
    }
}

// ---------------------------------------------------------------------------
// K_agg (R13-proven, 51.0 µs): wave-per-dst, 2 EDGES per iteration
// (eh = lane>>5 selects edge, g = lane&31 -> 4 channels). Cross-half merge
// via shfl_xor(32). Register accumulation, no atomics, fused epilogue.
// ---------------------------------------------------------------------------
__global__ __launch_bounds__(256) void k_agg(
    const int* __restrict__ offsets, const int* __restrict__ src_sorted,
    const float* __restrict__ a_s, const float* __restrict__ a_d,
    const unsigned int* __restrict__ h_bf, const unsigned int* __restrict__ r_bf,
    const float* __restrict__ bias, const float* __restrict__ res_b,
    const float* __restrict__ ln_g, const float* __restrict__ ln_b,
    float* __restrict__ out, int n)
{
    int wv = threadIdx.x >> 6, lane = threadIdx.x & 63;
    int d = blockIdx.x * 4 + wv;
    if (d >= n) return;
    int eh = lane >> 5, g = lane & 31;       // edge-half, channel group (4 ch)
    int head = g >> 3;
    float ad = a_d[d * NH + head];

    float a0 = 0.f, a1 = 0.f, a2 = 0.f, a3 = 0.f, denom = 0.f;

    // self-loop on eh=0 half only
    {
        float e = a_s[d * NH + head] + ad;
        e = (e >= 0.f) ? e : NEG_SLOPE * e;
        float w = (eh == 0) ? __expf(e) : 0.f;
        uint2 hv = *(const uint2*)&h_bf[d * 64 + 2 * g];
        a0 += w * __uint_as_float(hv.x << 16);
        a1 += w * __uint_as_float(hv.x & 0xffff0000u);
        a2 += w * __uint_as_float(hv.y << 16);
        a3 += w * __uint_as_float(hv.y & 0xffff0000u);
        denom += w;
    }

    int lo = offsets[d], hi = offsets[d + 1];
    int k = lo;
    // main loop: 4 pairs = 8 edges, all in-range
    for (; k + 7 < hi; k += 8) {
        int s[4]; float ee[4]; uint2 v[4];
#pragma unroll
        for (int i = 0; i < 4; ++i) s[i] = src_sorted[k + 2 * i + eh];
#pragma unroll
        for (int i = 0; i < 4; ++i) ee[i] = a_s[s[i] * NH + head];
#pragma unroll
        for (int i = 0; i < 4; ++i) v[i] = *(const uint2*)&h_bf[s[i] * 64 + 2 * g];
#pragma unroll
        for (int i = 0; i < 4; ++i) {
            float e0 = ee[i] + ad;
            e0 = (e0 >= 0.f) ? e0 : NEG_SLOPE * e0;
            float w0 = __expf(e0);
            denom += w0;
            a0 += w0 * __uint_as_float(v[i].x << 16);
            a1 += w0 * __uint_as_float(v[i].x & 0xffff0000u);
            a2 += w0 * __uint_as_float(v[i].y << 16);
            a3 += w0 * __uint_as_float(v[i].y & 0xffff0000u);
        }
    }
    // tail: pairs with per-lane guard
    for (; k < hi; k += 2) {
        int idx = k + eh;
        int valid = idx < hi;
        int s0 = valid ? src_sorted[idx] : 0;
        float e0 = a_s[s0 * NH + head] + ad;
        uint2 v0 = *(const uint2*)&h_bf[s0 * 64 + 2 * g];
        e0 = (e0 >= 0.f) ? e0 : NEG_SLOPE * e0;
        float w0 = valid ? __expf(e0) : 0.f;
        denom += w0;
        a0 += w0 * __uint_as_float(v0.x << 16);
        a1 += w0 * __uint_as_float(v0.x & 0xffff0000u);
        a2 += w0 * __uint_as_float(v0.y << 16);
        a3 += w0 * __uint_as_float(v0.y & 0xffff0000u);
    }

    // cross-half merge
    a0 += __shfl_xor(a0, 32, 64);
    a1 += __shfl_xor(a1, 32, 64);
    a2 += __shfl_xor(a2, 32, 64);
    a3 += __shfl_xor(a3, 32, 64);
    denom += __shfl_xor(denom, 32, 64);

    int c0 = g * 4;
    float4 bi = *(const float4*)&bias[c0];
    float4 rb = *(const float4*)&res_b[c0];
    float4 gg = *(const float4*)&ln_g[c0];
    float4 lb = *(const float4*)&ln_b[c0];
    uint2 rv = *(const uint2*)&r_bf[d * 64 + 2 * g];

    float inv = 1.f / denom;
    float o0 = a0 * inv + bi.x;
    float o1 = a1 * inv + bi.y;
    float o2 = a2 * inv + bi.z;
    float o3 = a3 * inv + bi.w;
    o0 = (o0 > 0.f) ? o0 : expm1f(o0);
    o1 = (o1 > 0.f) ? o1 : expm1f(o1);
    o2 = (o2 > 0.f) ? o2 : expm1f(o2);
    o3 = (o3 > 0.f) ? o3 : expm1f(o3);
    o0 += __uint_as_float(rv.x << 16) + rb.x;
    o1 += __uint_as_float(rv.x & 0xffff0000u) + rb.y;
    o2 += __uint_as_float(rv.y << 16) + rb.z;
    o3 += __uint_as_float(rv.y & 0xffff0000u) + rb.w;

    // LN: both halves hold identical values -> full-wave sum = 2x total
    float ps = o0 + o1 + o2 + o3;
#pragma unroll
    for (int off = 32; off > 0; off >>= 1) ps += __shfl_down(ps, off, 64);
    float mean = __shfl(ps, 0, 64) * (1.f / (2 * HC));
    float d0 = o0 - mean, d1 = o1 - mean, d2 = o2 - mean, d3 = o3 - mean;
    float pv = d0 * d0 + d1 * d1 + d2 * d2 + d3 * d3;
#pragma unroll
    for (int off = 32; off > 0; off >>= 1) pv += __shfl_down(pv, off, 64);
    float var = __shfl(pv, 0, 64) * (1.f / (2 * HC));
    float rs = rsqrtf(var + LN_EPS);
    if (eh == 0) {
        *(float4*)&out[d * HC + c0] =
            make_float4(gg.x * d0 * rs + lb.x, gg.y * d1 * rs + lb.y,
                        gg.z * d2 * rs + lb.z, gg.w * d3 * rs + lb.w);
    }
}

// ---------------------------------------------------------------------------
extern "C" void kernel_launch(void* const* d_in, const int* in_sizes, int n_in,
                              void* d_out, int out_size, void* d_ws, size_t ws_size,
                              hipStream_t stream) {
    const float* x       = (const float*)d_in[0];
    const int*   ei      = (const int*)d_in[1];
    const float* W       = (const float*)d_in[2];
    const float* att_src = (const float*)d_in[3];
    const float* att_dst = (const float*)d_in[4];
    const float* bias    = (const float*)d_in[5];
    const float* res_w   = (const float*)d_in[6];
    const float* res_b   = (const float*)d_in[7];
    const float* ln_g    = (const float*)d_in[8];
    const float* ln_b    = (const float*)d_in[9];
    float* out = (float*)d_out;

    int n = in_sizes[0] / F_IN;              // 50000 (<= 65536 for packing)
    int E = in_sizes[1] / 2;                 // 800000
    int NB = (n + BUCKET - 1) / BUCKET;      // 391 buckets (<= 512)
    int chunk = (E + NC_CHUNK - 1) / NC_CHUNK;
    int nka = (n + 63) / 64;                 // 782 kA blocks (1 set/wave)

    unsigned* h_bf     = (unsigned*)d_ws;                  // n*64 dwords
    unsigned* r_bf     = h_bf + (size_t)n * 64;            // n*64 dwords
    float*    a_s      = (float*)(r_bf + (size_t)n * 64);  // n*NH
    float*    a_d      = a_s + (size_t)n * NH;             // n*NH
    int*      counts   = (int*)(a_d + (size_t)n * NH);     // NC_CHUNK*NB
    int*      sbase_g  = counts + NC_CHUNK * NB;           // NB+1
    int*      epacked  = sbase_g + (NB + 2);               // E
    int*      ssorted  = epacked + E;                      // E
    int*      offsets  = ssorted + E;                      // n+1
    __bf16*   wt       = (__bf16*)(offsets + (n + 2));     // 256*64 bf16 = 32 KB

    k_prep<<<KW_BLOCKS + NC_CHUNK, 256, 0, stream>>>(
        W, res_w, ei, E, wt, counts, NB, chunk);

    k_main<<<nka + NC_CHUNK, 256, 0, stream>>>(
        x, wt, att_src, att_dst, h_bf, r_bf, a_s, a_d, n, nka,
        ei, E, counts, epacked, sbase_g, NB, chunk);

    kd_sort<<<NB, 256, 0, stream>>>(sbase_g, epacked, ssorted, offsets, NB, n, E);

    k_agg<<<(n + 3) / 4, 256, 0, stream>>>(offsets, ssorted, a_s, a_d, h_bf, r_bf,
                                           bias, res_b, ln_g, ln_b, out, n);
}

// Round 16
// 182.206 us; speedup vs baseline: 1.1292x; 1.0373x over previous
//
#include <hip/hip_runtime.h>

#define F_IN 64
#define NH 4
#define HC 128
#define NEG_SLOPE 0.2f
#define LN_EPS 1e-5f
#define NC_CHUNK 128          // number of edge chunks (quadratic prefix cost!)
#define BUCKET 128            // dst nodes per bucket
#define KW_BLOCKS 64          // blocks doing the W transpose in k_prep

typedef __bf16 bf16_8 __attribute__((ext_vector_type(8)));
typedef float  f32_4  __attribute__((ext_vector_type(4)));

// ---------------------------------------------------------------------------
// Inline per-wave int64-vs-int32 detection (all-zero odd dwords <=> int64).
// ---------------------------------------------------------------------------
__device__ inline int detect_is64(const int* __restrict__ ei, int E) {
    int lane = threadIdx.x & 63;
    long long stride = (2LL * E) / 65;
    int w = ei[(((long long)(lane + 1)) * stride) | 1];
    return __ballot(w != 0) == 0ULL;
}

__device__ inline unsigned bfpack(float a, float b) {
    unsigned ua = __float_as_uint(a), ub = __float_as_uint(b);
    ua = (ua + 0x7fffu + ((ua >> 16) & 1u)) >> 16;           // RNE to bf16
    ub = (ub + 0x7fffu + ((ub >> 16) & 1u)) >> 16;
    return ua | (ub << 16);
}

// ---------------------------------------------------------------------------
// K_prep: blocks [0,NC_CHUNK) = per-chunk dst-bucket histogram (LONG POLE,
// dispatched first); blocks [NC_CHUNK, NC_CHUNK+64) = Wcat transpose.
// ---------------------------------------------------------------------------
__global__ __launch_bounds__(256) void k_prep(
    const float* __restrict__ W, const float* __restrict__ res_w,
    const int* __restrict__ ei, int E,
    __bf16* __restrict__ wt, int* __restrict__ counts, int NB, int chunk)
{
    if ((int)blockIdx.x >= NC_CHUNK) {
        int idx = (blockIdx.x - NC_CHUNK) * 256 + threadIdx.x;   // 0..16383
        int ch = idx >> 6, k = idx & 63;
        const float* src = (ch < HC) ? W : res_w;
        wt[ch * 64 + k] = (__bf16)src[k * HC + (ch & (HC - 1))];
        return;
    }
    __shared__ int cnt[512];
    int c = blockIdx.x;
    for (int i = threadIdx.x; i < NB; i += 256) cnt[i] = 0;
    __syncthreads();
    int is64 = detect_is64(ei, E);
    int base = c * chunk, end = min(E, base + chunk);
    for (int idx = base + threadIdx.x; idx < end; idx += 256) {
        int d = is64 ? ei[2 * (E + idx)] : ei[E + idx];
        atomicAdd(&cnt[d >> 7], 1);
    }
    __syncthreads();
    for (int b = threadIdx.x; b < NB; b += 256)
        counts[c * NB + b] = cnt[b];
}

// ---------------------------------------------------------------------------
// K_main: blocks [0,NC_CHUNK) = kc_scatter (LONG POLE, dispatched first so it
// overlaps the kA phase); blocks [NC_CHUNK, NC_CHUNK+nka) = kA MFMA dual-GEMM
// (1 node-set/wave, 64 nodes/block, proven layout).
// ---------------------------------------------------------------------------
__global__ __launch_bounds__(256) void k_main(
    const float* __restrict__ x, const __bf16* __restrict__ wt,
    const float* __restrict__ att_src, const float* __restrict__ att_dst,
    unsigned* __restrict__ h_bf, unsigned* __restrict__ r_bf,
    float* __restrict__ a_s, float* __restrict__ a_d, int n, int nka,
    const int* __restrict__ ei, int E, const int* __restrict__ counts,
    int* __restrict__ epacked, int* __restrict__ sbase_g, int NB, int chunk)
{
    __shared__ int cur[512];
    __shared__ int ss[256];

    if ((int)blockIdx.x >= NC_CHUNK) {
        // ---------------- kA path (proven layout) ----------------
        int tid = threadIdx.x;
        int wv_ = tid >> 6, lane = tid & 63;
        int col = lane & 15, quad = lane >> 4;
        int node = (blockIdx.x - NC_CHUNK) * 64 + wv_ * 16 + col;
        int nrow = (node < n) ? node : (n - 1);

        bf16_8 bx0, bx1;
        {
            const float* xp = &x[nrow * F_IN + quad * 8];
            float4 p0 = *(const float4*)(xp);
            float4 p1 = *(const float4*)(xp + 4);
            float4 p2 = *(const float4*)(xp + 32);
            float4 p3 = *(const float4*)(xp + 36);
            bx0[0] = (__bf16)p0.x; bx0[1] = (__bf16)p0.y; bx0[2] = (__bf16)p0.z; bx0[3] = (__bf16)p0.w;
            bx0[4] = (__bf16)p1.x; bx0[5] = (__bf16)p1.y; bx0[6] = (__bf16)p1.z; bx0[7] = (__bf16)p1.w;
            bx1[0] = (__bf16)p2.x; bx1[1] = (__bf16)p2.y; bx1[2] = (__bf16)p2.z; bx1[3] = (__bf16)p2.w;
            bx1[4] = (__bf16)p3.x; bx1[5] = (__bf16)p3.y; bx1[6] = (__bf16)p3.z; bx1[7] = (__bf16)p3.w;
        }

        float vs[4] = {0.f, 0.f, 0.f, 0.f};
        float vd[4] = {0.f, 0.f, 0.f, 0.f};

#pragma unroll
        for (int mt = 0; mt < 16; ++mt) {
            const __bf16* ap = &wt[(mt * 16 + col) * 64 + quad * 8];
            bf16_8 a0 = *(const bf16_8*)ap;
            bf16_8 a1 = *(const bf16_8*)(ap + 32);
            f32_4 acc = {0.f, 0.f, 0.f, 0.f};
            acc = __builtin_amdgcn_mfma_f32_16x16x32_bf16(a0, bx0, acc, 0, 0, 0);
            acc = __builtin_amdgcn_mfma_f32_16x16x32_bf16(a1, bx1, acc, 0, 0, 0);
            int ch0 = mt * 16 + quad * 4;
            if (mt < 8) {
                float4 as4 = *(const float4*)&att_src[ch0];
                float4 ad4 = *(const float4*)&att_dst[ch0];
                int head = mt >> 1;
                vs[head] += acc[0] * as4.x + acc[1] * as4.y + acc[2] * as4.z + acc[3] * as4.w;
                vd[head] += acc[0] * ad4.x + acc[1] * ad4.y + acc[2] * ad4.z + acc[3] * ad4.w;
                if (node < n) {
                    uint2 pk = make_uint2(bfpack(acc[0], acc[1]), bfpack(acc[2], acc[3]));
                    *(uint2*)&h_bf[node * 64 + (ch0 >> 1)] = pk;
                }
            } else {
                if (node < n) {
                    uint2 pk = make_uint2(bfpack(acc[0], acc[1]), bfpack(acc[2], acc[3]));
                    *(uint2*)&r_bf[node * 64 + ((ch0 - 128) >> 1)] = pk;
                }
            }
        }

#pragma unroll
        for (int hh = 0; hh < NH; ++hh) {
            vs[hh] += __shfl_down(vs[hh], 32, 64);
            vs[hh] += __shfl_down(vs[hh], 16, 64);
            vd[hh] += __shfl_down(vd[hh], 32, 64);
            vd[hh] += __shfl_down(vd[hh], 16, 64);
        }
        if (quad == 0 && node < n) {
            *(float4*)&a_s[node * NH] = make_float4(vs[0], vs[1], vs[2], vs[3]);
            *(float4*)&a_d[node * NH] = make_float4(vd[0], vd[1], vd[2], vd[3]);
        }
        return;
    }

    // ---------------- scatter path (dispatched FIRST) ----------------
    int c = blockIdx.x;
    int t = threadIdx.x;
    int b0 = 2 * t, b1 = 2 * t + 1;

    int f0 = 0, f1 = 0, p0 = 0, p1 = 0;
    for (int cc = 0; cc < NC_CHUNK; ++cc) {
        int v0 = (b0 < NB) ? counts[cc * NB + b0] : 0;
        int v1 = (b1 < NB) ? counts[cc * NB + b1] : 0;
        f0 += v0; f1 += v1;
        if (cc < c) { p0 += v0; p1 += v1; }
    }
    ss[t] = f0 + f1;
    __syncthreads();
#pragma unroll
    for (int off = 1; off < 256; off <<= 1) {
        int u = (t >= off) ? ss[t - off] : 0;
        __syncthreads();
        ss[t] += u;
        __syncthreads();
    }
    int ebase = ss[t] - (f0 + f1);
    int base0 = ebase, base1 = ebase + f0;
    if (b0 < NB) cur[b0] = base0 + p0;
    if (b1 < NB) cur[b1] = base1 + p1;
    if (c == 0) {
        if (b0 <= NB) sbase_g[b0] = base0;
        if (b1 <= NB) sbase_g[b1] = base1;
    }
    __syncthreads();

    int is64 = detect_is64(ei, E);
    int base = c * chunk, end = min(E, base + chunk);
    int idx = base + t;
    // unroll-4: batch the (s,d) loads for memory-level parallelism
    for (; idx + 3 * 256 < end; idx += 4 * 256) {
        int i0 = idx, i1 = idx + 256, i2 = idx + 512, i3 = idx + 768;
        int s0, s1, s2, s3, d0, d1, d2, d3;
        if (is64) {
            s0 = ei[2 * i0]; s1 = ei[2 * i1]; s2 = ei[2 * i2]; s3 = ei[2 * i3];
            d0 = ei[2 * (E + i0)]; d1 = ei[2 * (E + i1)];
            d2 = ei[2 * (E + i2)]; d3 = ei[2 * (E + i3)];
        } else {
            s0 = ei[i0]; s1 = ei[i1]; s2 = ei[i2]; s3 = ei[i3];
            d0 = ei[E + i0]; d1 = ei[E + i1]; d2 = ei[E + i2]; d3 = ei[E + i3];
        }
        int q0 = atomicAdd(&cur[d0 >> 7], 1);
        epacked[q0] = ((d0 & (BUCKET - 1)) << 16) | s0;
        int q1 = atomicAdd(&cur[d1 >> 7], 1);
        epacked[q1] = ((d1 & (BUCKET - 1)) << 16) | s1;
        int q2 = atomicAdd(&cur[d2 >> 7], 1);
        epacked[q2] = ((d2 & (BUCKET - 1)) << 16) | s2;
        int q3 = atomicAdd(&cur[d3 >> 7], 1);
        epacked[q3] = ((d3 & (BUCKET - 1)) << 16) | s3;
    }
    for (; idx < end; idx += 256) {
        int s = is64 ? ei[2 * idx] : ei[idx];
        int d = is64 ? ei[2 * (E + idx)] : ei[E + idx];
        int p = atomicAdd(&cur[d >> 7], 1);
        epacked[p] = ((d & (BUCKET - 1)) << 16) | s;
    }
}

// ---------------------------------------------------------------------------
// KD_sort: one block per bucket -> per-dst CSR order; emits node offsets.
// ---------------------------------------------------------------------------
__global__ __launch_bounds__(256) void kd_sort(
    const int* __restrict__ sbase_g, const int* __restrict__ epacked,
    int* __restrict__ sorted_src, int* __restrict__ offsets,
    int NB, int n, int E)
{
    __shared__ int hist[BUCKET];
    __shared__ int sc[BUCKET];
    __shared__ int cur[BUCKET];
    int b = blockIdx.x;
    int s0 = sbase_g[b];
    int s1 = sbase_g[b + 1];
    int t = threadIdx.x;
    if (t < BUCKET) hist[t] = 0;
    __syncthreads();
    for (int e = s0 + t; e < s1; e += 256)
        atomicAdd(&hist[((unsigned)epacked[e]) >> 16], 1);
    __syncthreads();
    if (t < BUCKET) sc[t] = hist[t];
    __syncthreads();
#pragma unroll
    for (int o = 1; o < BUCKET; o <<= 1) {
        int u = (t >= o && t < BUCKET) ? sc[t - o] : 0;
        __syncthreads();
        if (t < BUCKET) sc[t] += u;
        __syncthreads();
    }
    if (t < BUCKET) {
        int excl = sc[t] - hist[t];
        cur[t] = s0 + excl;
        int d = b * BUCKET + t;
        if (d < n) offsets[d] = s0 + excl;
    }
    if (b == NB - 1 && t == 0) offsets[n] = E;
    __syncthreads();
    for (int e = s0 + t; e < s1; e += 256) {
        int p = epacked[e];
        int pos = atomicAdd(&cur[((unsigned)p) >> 16], 1);
        sorted_src[pos] = p & 0xFFFF;
    }
}

// ---------------------------------------------------------------------------
// K_agg (R13/R15-proven, 51 µs): wave-per-dst, 2 EDGES per iteration
// (eh = lane>>5 selects edge, g = lane&31 -> 4 channels). Cross-half merge
// via shfl_xor(32). Register accumulation, no atomics, fused epilogue.
// ---------------------------------------------------------------------------
__global__ __launch_bounds__(256) void k_agg(
    const int* __restrict__ offsets, const int* __restrict__ src_sorted,
    const float* __restrict__ a_s, const float* __restrict__ a_d,
    const unsigned int* __restrict__ h_bf, const unsigned int* __restrict__ r_bf,
    const float* __restrict__ bias, const float* __restrict__ res_b,
    const float* __restrict__ ln_g, const float* __restrict__ ln_b,
    float* __restrict__ out, int n)
{
    int wv = threadIdx.x >> 6, lane = threadIdx.x & 63;
    int d = blockIdx.x * 4 + wv;
    if (d >= n) return;
    int eh = lane >> 5, g = lane & 31;       // edge-half, channel group (4 ch)
    int head = g >> 3;
    float ad = a_d[d * NH + head];

    float a0 = 0.f, a1 = 0.f, a2 = 0.f, a3 = 0.f, denom = 0.f;

    // self-loop on eh=0 half only
    {
        float e = a_s[d * NH + head] + ad;
        e = (e >= 0.f) ? e : NEG_SLOPE * e;
        float w = (eh == 0) ? __expf(e) : 0.f;
        uint2 hv = *(const uint2*)&h_bf[d * 64 + 2 * g];
        a0 += w * __uint_as_float(hv.x << 16);
        a1 += w * __uint_as_float(hv.x & 0xffff0000u);
        a2 += w * __uint_as_float(hv.y << 16);
        a3 += w * __uint_as_float(hv.y & 0xffff0000u);
        denom += w;
    }

    int lo = offsets[d], hi = offsets[d + 1];
    int k = lo;
    // main loop: 4 pairs = 8 edges, all in-range
    for (; k + 7 < hi; k += 8) {
        int s[4]; float ee[4]; uint2 v[4];
#pragma unroll
        for (int i = 0; i < 4; ++i) s[i] = src_sorted[k + 2 * i + eh];
#pragma unroll
        for (int i = 0; i < 4; ++i) ee[i] = a_s[s[i] * NH + head];
#pragma unroll
        for (int i = 0; i < 4; ++i) v[i] = *(const uint2*)&h_bf[s[i] * 64 + 2 * g];
#pragma unroll
        for (int i = 0; i < 4; ++i) {
            float e0 = ee[i] + ad;
            e0 = (e0 >= 0.f) ? e0 : NEG_SLOPE * e0;
            float w0 = __expf(e0);
            denom += w0;
            a0 += w0 * __uint_as_float(v[i].x << 16);
            a1 += w0 * __uint_as_float(v[i].x & 0xffff0000u);
            a2 += w0 * __uint_as_float(v[i].y << 16);
            a3 += w0 * __uint_as_float(v[i].y & 0xffff0000u);
        }
    }
    // tail: pairs with per-lane guard
    for (; k < hi; k += 2) {
        int idx = k + eh;
        int valid = idx < hi;
        int s0 = valid ? src_sorted[idx] : 0;
        float e0 = a_s[s0 * NH + head] + ad;
        uint2 v0 = *(const uint2*)&h_bf[s0 * 64 + 2 * g];
        e0 = (e0 >= 0.f) ? e0 : NEG_SLOPE * e0;
        float w0 = valid ? __expf(e0) : 0.f;
        denom += w0;
        a0 += w0 * __uint_as_float(v0.x << 16);
        a1 += w0 * __uint_as_float(v0.x & 0xffff0000u);
        a2 += w0 * __uint_as_float(v0.y << 16);
        a3 += w0 * __uint_as_float(v0.y & 0xffff0000u);
    }

    // cross-half merge
    a0 += __shfl_xor(a0, 32, 64);
    a1 += __shfl_xor(a1, 32, 64);
    a2 += __shfl_xor(a2, 32, 64);
    a3 += __shfl_xor(a3, 32, 64);
    denom += __shfl_xor(denom, 32, 64);

    int c0 = g * 4;
    float4 bi = *(const float4*)&bias[c0];
    float4 rb = *(const float4*)&res_b[c0];
    float4 gg = *(const float4*)&ln_g[c0];
    float4 lb = *(const float4*)&ln_b[c0];
    uint2 rv = *(const uint2*)&r_bf[d * 64 + 2 * g];

    float inv = 1.f / denom;
    float o0 = a0 * inv + bi.x;
    float o1 = a1 * inv + bi.y;
    float o2 = a2 * inv + bi.z;
    float o3 = a3 * inv + bi.w;
    o0 = (o0 > 0.f) ? o0 : expm1f(o0);
    o1 = (o1 > 0.f) ? o1 : expm1f(o1);
    o2 = (o2 > 0.f) ? o2 : expm1f(o2);
    o3 = (o3 > 0.f) ? o3 : expm1f(o3);
    o0 += __uint_as_float(rv.x << 16) + rb.x;
    o1 += __uint_as_float(rv.x & 0xffff0000u) + rb.y;
    o2 += __uint_as_float(rv.y << 16) + rb.z;
    o3 += __uint_as_float(rv.y & 0xffff0000u) + rb.w;

    // LN: both halves hold identical values -> full-wave sum = 2x total
    float ps = o0 + o1 + o2 + o3;
#pragma unroll
    for (int off = 32; off > 0; off >>= 1) ps += __shfl_down(ps, off, 64);
    float mean = __shfl(ps, 0, 64) * (1.f / (2 * HC));
    float d0 = o0 - mean, d1 = o1 - mean, d2 = o2 - mean, d3 = o3 - mean;
    float pv = d0 * d0 + d1 * d1 + d2 * d2 + d3 * d3;
#pragma unroll
    for (int off = 32; off > 0; off >>= 1) pv += __shfl_down(pv, off, 64);
    float var = __shfl(pv, 0, 64) * (1.f / (2 * HC));
    float rs = rsqrtf(var + LN_EPS);
    if (eh == 0) {
        *(float4*)&out[d * HC + c0] =
            make_float4(gg.x * d0 * rs + lb.x, gg.y * d1 * rs + lb.y,
                        gg.z * d2 * rs + lb.z, gg.w * d3 * rs + lb.w);
    }
}

// ---------------------------------------------------------------------------
extern "C" void kernel_launch(void* const* d_in, const int* in_sizes, int n_in,
                              void* d_out, int out_size, void* d_ws, size_t ws_size,
                              hipStream_t stream) {
    const float* x       = (const float*)d_in[0];
    const int*   ei      = (const int*)d_in[1];
    const float* W       = (const float*)d_in[2];
    const float* att_src = (const float*)d_in[3];
    const float* att_dst = (const float*)d_in[4];
    const float* bias    = (const float*)d_in[5];
    const float* res_w   = (const float*)d_in[6];
    const float* res_b   = (const float*)d_in[7];
    const float* ln_g    = (const float*)d_in[8];
    const float* ln_b    = (const float*)d_in[9];
    float* out = (float*)d_out;

    int n = in_sizes[0] / F_IN;              // 50000 (<= 65536 for packing)
    int E = in_sizes[1] / 2;                 // 800000
    int NB = (n + BUCKET - 1) / BUCKET;      // 391 buckets (<= 512)
    int chunk = (E + NC_CHUNK - 1) / NC_CHUNK;
    int nka = (n + 63) / 64;                 // 782 kA blocks (1 set/wave)

    unsigned* h_bf     = (unsigned*)d_ws;                  // n*64 dwords
    unsigned* r_bf     = h_bf + (size_t)n * 64;            // n*64 dwords
    float*    a_s      = (float*)(r_bf + (size_t)n * 64);  // n*NH
    float*    a_d      = a_s + (size_t)n * NH;             // n*NH
    int*      counts   = (int*)(a_d + (size_t)n * NH);     // NC_CHUNK*NB
    int*      sbase_g  = counts + NC_CHUNK * NB;           // NB+1
    int*      epacked  = sbase_g + (NB + 2);               // E
    int*      ssorted  = epacked + E;                      // E
    int*      offsets  = ssorted + E;                      // n+1
    __bf16*   wt       = (__bf16*)(offsets + (n + 2));     // 256*64 bf16 = 32 KB

    k_prep<<<NC_CHUNK + KW_BLOCKS, 256, 0, stream>>>(
        W, res_w, ei, E, wt, counts, NB, chunk);

    k_main<<<NC_CHUNK + nka, 256, 0, stream>>>(
        x, wt, att_src, att_dst, h_bf, r_bf, a_s, a_d, n, nka,
        ei, E, counts, epacked, sbase_g, NB, chunk);

    kd_sort<<<NB, 256, 0, stream>>>(sbase_g, epacked, ssorted, offsets, NB, n, E);

    k_agg<<<(n + 3) / 4, 256, 0, stream>>>(offsets, ssorted, a_s, a_d, h_bf, r_bf,
                                           bias, res_b, ln_g, ln_b, out, n);
}